// Round 12
// baseline (264.977 us; speedup 1.0000x reference)
//
#include <hip/hip_runtime.h>

typedef unsigned int u32;
typedef unsigned short u16;
typedef __bf16 bf16x8 __attribute__((ext_vector_type(8)));
typedef float f32x4 __attribute__((ext_vector_type(4)));

#define HIDDEN 2048
#define HEADS 16
#define HDIM 128
#define SEQ 1024
#define BATCH 2
#define ROWS (BATCH*SEQ)
#define SCALE 0.08838834764831845f   /* 128^-0.5 */
#define GSC 0.1f

__device__ __forceinline__ u16 f2bf(float f) {
    u32 x = __builtin_bit_cast(u32, f);
    x += 0x7fffu + ((x >> 16) & 1u);          // RNE
    return (u16)(x >> 16);
}
__device__ __forceinline__ float bf2f(u16 u) {
    return __builtin_bit_cast(float, ((u32)u) << 16);
}
__device__ __forceinline__ void gld_lds16(const void* g, void* l) {
    __builtin_amdgcn_global_load_lds((const __attribute__((address_space(1))) u32*)g,
                                     (__attribute__((address_space(3))) u32*)l, 16, 0, 0);
}

// ---------------- prep mega: x->bf16 (4096 blocks) | W^T bf16 (16384) | rope tables (256)
__global__ __launch_bounds__(256) void k_prep(
    const float* __restrict__ x, u16* __restrict__ xb,
    const float* __restrict__ W0, const float* __restrict__ W1,
    const float* __restrict__ W2, const float* __restrict__ W3,
    u16* __restrict__ T0, u16* __restrict__ T1, u16* __restrict__ T2, u16* __restrict__ T3,
    float* __restrict__ cosT, float* __restrict__ sinT) {
    __shared__ float t[32][33];
    const int bid = blockIdx.x;
    const int tid = threadIdx.x;
    if (bid < 4096) {                         // ---- cvt ----
        const int i = (bid * 256 + tid) * 4;
        float4 v = *(const float4*)(x + i);
        uint2 r;
        r.x = (u32)f2bf(v.x) | ((u32)f2bf(v.y) << 16);
        r.y = (u32)f2bf(v.z) | ((u32)f2bf(v.w) << 16);
        *(uint2*)(xb + i) = r;
    } else if (bid < 4096 + 16384) {          // ---- weight transpose+cvt ----
        const int idx = bid - 4096;
        const int bx = (idx & 63) * 32, by = ((idx >> 6) & 63) * 32, z = idx >> 12;
        const float* W = (z == 0) ? W0 : (z == 1) ? W1 : (z == 2) ? W2 : W3;
        u16* Wt = (z == 0) ? T0 : (z == 1) ? T1 : (z == 2) ? T2 : T3;
        const int tx = tid & 31, ty = tid >> 5;
#pragma unroll
        for (int yy = 0; yy < 32; yy += 8)
            t[ty + yy][tx] = W[(size_t)(by + ty + yy) * HIDDEN + bx + tx];
        __syncthreads();
#pragma unroll
        for (int yy = 0; yy < 32; yy += 8)
            Wt[(size_t)(bx + ty + yy) * HIDDEN + by + tx] = f2bf(t[tx][ty + yy]);
    } else {                                  // ---- rope tables ----
        const int i = (bid - 20480) * 256 + tid;   // 65536
        const int s = i >> 6, d = i & 63;
        const float inv = expf(-(float)d * 0.14391156831f);  // ln(10000)/64
        const float fr = (float)s * inv;
        cosT[i] = cosf(fr);
        sinT[i] = sinf(fr);
    }
}

// ---------------- QKV GEMM: 256x256 tile, counted-vmcnt double-buffer (T4+T5) ----------
__global__ __launch_bounds__(512, 2) void k_qkv(
    const u16* __restrict__ Ag, const u16* __restrict__ Bg,
    u16* __restrict__ qo, u16* __restrict__ ko, u16* __restrict__ vo) {
    __shared__ __align__(16) u16 As[2][16384];   // [buf][256 rows x 64 k]
    __shared__ __align__(16) u16 Bs[2][16384];
    const int tid = threadIdx.x;
    const int l = tid & 63, wid = tid >> 6;
    const int wr = wid >> 2, wc = wid & 3;          // 2 x 4 waves
    const int g = l >> 4, l15 = l & 15;
    const int bid = blockIdx.x;                     // 0..191
    const int idx = bid >> 3;                       // 0..23
    const int nt = (bid & 7) * 3 + idx % 3;         // 0..23
    const int mt = idx / 3;                         // 0..7
    const int m0 = mt * 256, n0 = nt * 256;
    const int swxe = (l15 & 7) << 3;                // read-side XOR (elements)
    int srow[4], scol[4];
#pragma unroll
    for (int p = 0; p < 4; ++p) {
        const int o = p * 8192 + tid * 16;
        const int r = o >> 7;
        srow[p] = r;
        scol[p] = ((o & 127) ^ ((r & 7) << 4)) >> 1;
    }
    f32x4 acc[8][4] = {};
    constexpr int NT = HIDDEN / 64;                 // 32 K-tiles

#pragma unroll
    for (int p = 0; p < 4; ++p)
        gld_lds16(Ag + (size_t)(m0 + srow[p]) * HIDDEN + scol[p], &As[0][p * 4096 + tid * 8]);
#pragma unroll
    for (int p = 0; p < 4; ++p)
        gld_lds16(Bg + (size_t)(n0 + srow[p]) * HIDDEN + scol[p], &Bs[0][p * 4096 + tid * 8]);

    for (int i = 0; i < NT; ++i) {
        const int cur = i & 1, nb = cur ^ 1;
        const bool more = (i + 1 < NT);
        if (more) {
            const int kk1 = (i + 1) * 64;
#pragma unroll
            for (int p = 0; p < 4; ++p)
                gld_lds16(Ag + (size_t)(m0 + srow[p]) * HIDDEN + kk1 + scol[p],
                          &As[nb][p * 4096 + tid * 8]);
#pragma unroll
            for (int p = 0; p < 4; ++p)
                gld_lds16(Bg + (size_t)(n0 + srow[p]) * HIDDEN + kk1 + scol[p],
                          &Bs[nb][p * 4096 + tid * 8]);
        }
        if (more) asm volatile("s_waitcnt vmcnt(8)" ::: "memory");
        else      asm volatile("s_waitcnt vmcnt(0)" ::: "memory");
        __builtin_amdgcn_sched_barrier(0);
        __builtin_amdgcn_s_barrier();
        bf16x8 bfr[4][2];
#pragma unroll
        for (int n = 0; n < 4; ++n)
#pragma unroll
            for (int ks = 0; ks < 2; ++ks)
                bfr[n][ks] = *(const bf16x8*)&Bs[cur][(wc * 64 + n * 16 + l15) * 64 +
                                                      ((ks * 32 + g * 8) ^ swxe)];
        __builtin_amdgcn_s_setprio(1);
#pragma unroll
        for (int m = 0; m < 8; ++m) {
            bf16x8 a0 = *(const bf16x8*)&As[cur][(wr * 128 + m * 16 + l15) * 64 +
                                                 ((g * 8) ^ swxe)];
            bf16x8 a1 = *(const bf16x8*)&As[cur][(wr * 128 + m * 16 + l15) * 64 +
                                                 ((32 + g * 8) ^ swxe)];
#pragma unroll
            for (int n = 0; n < 4; ++n) {
                acc[m][n] = __builtin_amdgcn_mfma_f32_16x16x32_bf16(a0, bfr[n][0], acc[m][n], 0, 0, 0);
                acc[m][n] = __builtin_amdgcn_mfma_f32_16x16x32_bf16(a1, bfr[n][1], acc[m][n], 0, 0, 0);
            }
        }
        __builtin_amdgcn_s_setprio(0);
        asm volatile("s_waitcnt lgkmcnt(0)" ::: "memory");
        __builtin_amdgcn_sched_barrier(0);
        __builtin_amdgcn_s_barrier();
    }
    u16* Cb = (nt < 8) ? qo : (nt < 16) ? ko : vo;
    const int nloc = n0 & 2047;
#pragma unroll
    for (int m = 0; m < 8; ++m)
#pragma unroll
        for (int n = 0; n < 4; ++n) {
            const int col = nloc + wc * 64 + n * 16 + l15;
#pragma unroll
            for (int j = 0; j < 4; ++j) {
                const int row = m0 + wr * 128 + m * 16 + g * 4 + j;
                Cb[(size_t)row * HIDDEN + col] = f2bf(acc[m][n][j]);
            }
        }
}

// ---------------- mid mega: RoPE in place (8192 blocks) | v -> vT (4096) ----------------
__global__ __launch_bounds__(256) void k_mid(
    u16* __restrict__ q, u16* __restrict__ k,
    const float* __restrict__ cosT, const float* __restrict__ sinT,
    const u16* __restrict__ v, u16* __restrict__ vT) {
    __shared__ u16 t[32][33];
    const int bid = blockIdx.x;
    const int tid = threadIdx.x;
    if (bid < 8192) {                          // ---- rope ----
        const int i = bid * 256 + tid;         // 2M
        const int row = i >> 10;
        const int hd = i & 1023;
        const int h = hd >> 6, d = hd & 63;
        const int s = row & (SEQ - 1);
        const float c = cosT[s * 64 + d], sn = sinT[s * 64 + d];
        const size_t o1 = (size_t)row * HIDDEN + h * HDIM + d;
        const size_t o2 = o1 + 64;
        float x1 = bf2f(q[o1]), x2 = bf2f(q[o2]);
        q[o1] = f2bf(x1 * c - x2 * sn);
        q[o2] = f2bf(x2 * c + x1 * sn);
        float y1 = bf2f(k[o1]), y2 = bf2f(k[o2]);
        k[o1] = f2bf(y1 * c - y2 * sn);
        k[o2] = f2bf(y2 * c + y1 * sn);
    } else {                                   // ---- v transpose ----
        const int idx = bid - 8192;
        const int s0 = (idx & 31) * 32, d0 = ((idx >> 5) & 3) * 32, bh = idx >> 7;
        const int b = bh >> 4, h = bh & 15;
        const int tx = tid & 31, ty = tid >> 5;
#pragma unroll
        for (int yy = 0; yy < 32; yy += 8)
            t[ty + yy][tx] = v[(size_t)(b * SEQ + s0 + ty + yy) * HIDDEN + h * HDIM + d0 + tx];
        __syncthreads();
#pragma unroll
        for (int yy = 0; yy < 32; yy += 8)
            vT[((size_t)bh * HDIM + d0 + ty + yy) * SEQ + s0 + tx] = t[tx][ty + yy];
    }
}

// ---------------- fused causal attention + in-register governance bias ------------------
// 4-wave blocks (64 q-rows), double-buffered K/V LDS, counted-vmcnt protocol (R9-proven):
// stage KV(kt+1) + masks(kt+1) -> vmcnt(20) -> barrier -> compute(kt) -> lgkm(0) -> barrier.
// Next tile's 20 loads stay in flight across the whole tile compute.
__global__ __launch_bounds__(256) void k_attn(
    const u16* __restrict__ qraw, const u16* __restrict__ kraw, const u16* __restrict__ vT,
    const float* __restrict__ pm, const float* __restrict__ po, const float* __restrict__ mw,
    u16* __restrict__ attnb) {
    __shared__ __align__(16) u16 Ks[2][64 * 128];
    __shared__ __align__(16) u16 Vs[2][128 * 64];
    __shared__ __align__(16) u16 Pl[4][16 * 72];
    const int tid = threadIdx.x;
    const int ln = tid & 63, w = tid >> 6;
    const int g = ln >> 4, q15 = ln & 15;
    // XCD chunk (512 blocks, 64/XCD, all co-resident at 2 blocks/CU) + exact LPT pairing:
    // qb pairs (15,0),(13,2),... -> every CU's two blocks sum to 17 k-tiles.
    const int j = blockIdx.x;           // 0..511
    const int p = j >> 3;               // 0..63 within XCD chunk
    const int y = (j & 7) * 4 + (p & 3);
    const int t = p >> 2;               // 0..15
    const int qb = (t < 8) ? (15 - 2 * t) : (2 * (t - 8));
    const int b = y >> 4, h = y & 15;
    const int q0 = qb * 64;
    const int qw = q0 + w * 16;
    const int qg = qw + q15;
    const int ktmax = qb;
    const int k_r = tid >> 4;                                  // 0..15
    const int k_c = ((tid & 15) * 8) ^ ((k_r & 7) << 3);
    const int v_r = tid >> 3;                                  // 0..31
    const int v_c = ((tid & 7) * 8) ^ ((v_r & 7) << 3);
    const int sw = (q15 & 7) << 3;
    bf16x8 qf[4];
    {
        const size_t qoff = (size_t)(b * SEQ + qg) * HIDDEN + h * HDIM;
#pragma unroll
        for (int ds = 0; ds < 4; ++ds) qf[ds] = *(const bf16x8*)(qraw + qoff + ds * 32 + g * 8);
    }
    f32x4 acc_o[8] = {};
    float m_run = -1e30f, l_run = 0.f;
    u16* pw = &Pl[w][0];
    const u16* krow = kraw + (size_t)(b * SEQ) * HIDDEN + h * HDIM;
    const u16* vrow = vT + (size_t)y * HDIM * SEQ;
    const size_t mbase = ((size_t)y * SEQ + qg) * SEQ + g * 4;
    const float* pmr = pm + mbase;
    const float* por = po + mbase;
    const float* mwr = mw + mbase;

    auto stage_kv = [&](int kt, int bufi) {
        const int k0 = kt * 64;
#pragma unroll
        for (int c = 0; c < 4; ++c)
            gld_lds16(krow + (size_t)(k0 + c * 16 + k_r) * HIDDEN + k_c,
                      &Ks[bufi][c * 2048 + tid * 8]);
#pragma unroll
        for (int c = 0; c < 4; ++c)
            gld_lds16(vrow + (size_t)(c * 32 + v_r) * SEQ + k0 + v_c,
                      &Vs[bufi][c * 2048 + tid * 8]);
    };
    float4 mA[12], mB[12];
    auto issue_masks = [&](float4 (&mm)[12], int kt) {
        const int c = kt * 64;
#pragma unroll
        for (int m = 0; m < 4; ++m) {
            mm[m * 3 + 0] = *(const float4*)(pmr + c + m * 16);
            mm[m * 3 + 1] = *(const float4*)(por + c + m * 16);
            mm[m * 3 + 2] = *(const float4*)(mwr + c + m * 16);
        }
    };

    auto step = [&](int kt, float4 (&cur)[12], float4 (&nxt)[12]) {
        const int bufi = kt & 1;
        const bool more = (kt < ktmax);
        // (1) stage next tile's K/V (8 gld_lds) + masks (12 reg loads): 20 in flight
        if (more) {
            stage_kv(kt + 1, bufi ^ 1);
            issue_masks(nxt, kt + 1);
        }
        // (2) counted wait BEFORE barrier: tile kt's loads retired; barrier => all waves'
        if (more) asm volatile("s_waitcnt vmcnt(20)" ::: "memory");
        else      asm volatile("s_waitcnt vmcnt(0)" ::: "memory");
        __builtin_amdgcn_sched_barrier(0);
        __builtin_amdgcn_s_barrier();
        // (3) QK^T from Ks[bufi]
        const int k0 = kt * 64;
        f32x4 accs[4] = {};
#pragma unroll
        for (int ds = 0; ds < 4; ++ds)
#pragma unroll
            for (int m = 0; m < 4; ++m) {
                bf16x8 kf = *(const bf16x8*)&Ks[bufi][(m * 16 + q15) * 128 +
                                                      ((ds * 32 + g * 8) ^ sw)];
                accs[m] = __builtin_amdgcn_mfma_f32_16x16x32_bf16(kf, qf[ds], accs[m], 0, 0, 0);
            }
        // (4) bias + causal + online softmax
        float pmax = -1e30f;
#pragma unroll
        for (int m = 0; m < 4; ++m) {
            const float4 av = cur[m * 3 + 0];
            const float4 bv4 = cur[m * 3 + 1];
            const float4 cv = cur[m * 3 + 2];
#pragma unroll
            for (int r = 0; r < 4; ++r) {
                const int kglob = k0 + m * 16 + g * 4 + r;
                const float bias = (&av.x)[r] * (GSC * 0.5f) + (&bv4.x)[r] * GSC +
                                   __logf(fmaf((&cv.x)[r], GSC, 1.0f + 1e-8f));
                float s = (kglob <= qg) ? fmaf(accs[m][r], SCALE, bias) : -1e30f;
                accs[m][r] = s;
                pmax = fmaxf(pmax, s);
            }
        }
        pmax = fmaxf(pmax, __shfl_xor(pmax, 16));
        pmax = fmaxf(pmax, __shfl_xor(pmax, 32));
        const float mnew = fmaxf(m_run, pmax);
        const float alpha = __expf(m_run - mnew);
        float lsum = 0.f;
#pragma unroll
        for (int m = 0; m < 4; ++m)
#pragma unroll
            for (int r = 0; r < 4; ++r) {
                float e = __expf(accs[m][r] - mnew);
                accs[m][r] = e;
                lsum += e;
            }
        lsum += __shfl_xor(lsum, 16);
        lsum += __shfl_xor(lsum, 32);
        l_run = l_run * alpha + lsum;
        m_run = mnew;
#pragma unroll
        for (int m = 0; m < 4; ++m) {
            uint2 pk;
            pk.x = (u32)f2bf(accs[m][0]) | ((u32)f2bf(accs[m][1]) << 16);
            pk.y = (u32)f2bf(accs[m][2]) | ((u32)f2bf(accs[m][3]) << 16);
            *(uint2*)&pw[q15 * 72 + m * 16 + g * 4] = pk;
        }
        float al[4];
#pragma unroll
        for (int jj = 0; jj < 4; ++jj) al[jj] = __shfl(alpha, g * 4 + jj);
#pragma unroll
        for (int n = 0; n < 8; ++n)
#pragma unroll
            for (int jj = 0; jj < 4; ++jj) acc_o[n][jj] *= al[jj];
        // (5) PV from Vs[bufi]
#pragma unroll
        for (int c = 0; c < 2; ++c) {
            const bf16x8 af = *(const bf16x8*)&pw[q15 * 72 + c * 32 + g * 8];
#pragma unroll
            for (int n = 0; n < 8; ++n) {
                const bf16x8 vf = *(const bf16x8*)&Vs[bufi][(n * 16 + q15) * 64 +
                                                           ((c * 32 + g * 8) ^ sw)];
                acc_o[n] = __builtin_amdgcn_mfma_f32_16x16x32_bf16(af, vf, acc_o[n], 0, 0, 0);
            }
        }
        // (6) LDS reads done -> safe for next overwrite after barrier
        asm volatile("s_waitcnt lgkmcnt(0)" ::: "memory");
        __builtin_amdgcn_sched_barrier(0);
        __builtin_amdgcn_s_barrier();
    };

    stage_kv(0, 0);
    issue_masks(mA, 0);
    int kt = 0;
    for (;;) {
        step(kt, mA, mB);
        if (kt == ktmax) break;
        ++kt;
        step(kt, mB, mA);
        if (kt == ktmax) break;
        ++kt;
    }

    const float linv = 1.0f / l_run;
    float li[4];
#pragma unroll
    for (int jj = 0; jj < 4; ++jj) li[jj] = __shfl(linv, g * 4 + jj);
#pragma unroll
    for (int n = 0; n < 8; ++n)
#pragma unroll
        for (int jj = 0; jj < 4; ++jj) {
            const int row = b * SEQ + qw + g * 4 + jj;
            const int col = h * HDIM + n * 16 + q15;
            attnb[(size_t)row * HIDDEN + col] = f2bf(acc_o[n][jj] * li[jj]);
        }
}

// ---------------- output GEMM: 128x128 tile, counted-vmcnt double-buffer ----------------
__global__ __launch_bounds__(256) void k_out(
    const u16* __restrict__ A, const u16* __restrict__ Bt,
    float* __restrict__ Cf, const float* __restrict__ bias) {
    __shared__ __align__(16) u16 As[2][8192];    // [buf][128 rows x 64 k]
    __shared__ __align__(16) u16 Bs[2][8192];
    const int tid = threadIdx.x;
    const int l = tid & 63, wid = tid >> 6;
    const int wr = wid >> 1, wc = wid & 1;        // 2 x 2 waves
    const int g = l >> 4, l15 = l & 15;
    const int bid = blockIdx.x;                   // 0..255, XCD-bijective (256%8==0)
    const int rr = (bid & 7) * 32 + (bid >> 3);
    const int mt = rr >> 4, nt = rr & 15;
    const int m0 = mt * 128, n0 = nt * 128;
    const int swxe = (l15 & 7) << 3;
    int srow[4], scol[4];
#pragma unroll
    for (int p = 0; p < 4; ++p) {
        const int o = p * 4096 + tid * 16;
        const int r = o >> 7;                     // 0..127
        srow[p] = r;
        scol[p] = ((o & 127) ^ ((r & 7) << 4)) >> 1;
    }
    f32x4 acc[4][4] = {};
    constexpr int NT = HIDDEN / 64;               // 32 K-tiles

#pragma unroll
    for (int p = 0; p < 4; ++p) {
        gld_lds16(A + (size_t)(m0 + srow[p]) * HIDDEN + scol[p], &As[0][p * 2048 + tid * 8]);
        gld_lds16(Bt + (size_t)(n0 + srow[p]) * HIDDEN + scol[p], &Bs[0][p * 2048 + tid * 8]);
    }

    for (int i = 0; i < NT; ++i) {
        const int cur = i & 1, nb = cur ^ 1;
        const bool more = (i + 1 < NT);
        if (more) {
            const int kk1 = (i + 1) * 64;
#pragma unroll
            for (int p = 0; p < 4; ++p) {
                gld_lds16(A + (size_t)(m0 + srow[p]) * HIDDEN + kk1 + scol[p],
                          &As[nb][p * 2048 + tid * 8]);
                gld_lds16(Bt + (size_t)(n0 + srow[p]) * HIDDEN + kk1 + scol[p],
                          &Bs[nb][p * 2048 + tid * 8]);
            }
        }
        if (more) asm volatile("s_waitcnt vmcnt(8)" ::: "memory");
        else      asm volatile("s_waitcnt vmcnt(0)" ::: "memory");
        __builtin_amdgcn_sched_barrier(0);
        __builtin_amdgcn_s_barrier();
        bf16x8 bfr[4][2];
#pragma unroll
        for (int n = 0; n < 4; ++n)
#pragma unroll
            for (int ks = 0; ks < 2; ++ks)
                bfr[n][ks] = *(const bf16x8*)&Bs[cur][(wc * 64 + n * 16 + l15) * 64 +
                                                      ((ks * 32 + g * 8) ^ swxe)];
        __builtin_amdgcn_s_setprio(1);
#pragma unroll
        for (int m = 0; m < 4; ++m) {
            bf16x8 a0 = *(const bf16x8*)&As[cur][(wr * 64 + m * 16 + l15) * 64 +
                                                 ((g * 8) ^ swxe)];
            bf16x8 a1 = *(const bf16x8*)&As[cur][(wr * 64 + m * 16 + l15) * 64 +
                                                 ((32 + g * 8) ^ swxe)];
#pragma unroll
            for (int n = 0; n < 4; ++n) {
                acc[m][n] = __builtin_amdgcn_mfma_f32_16x16x32_bf16(a0, bfr[n][0], acc[m][n], 0, 0, 0);
                acc[m][n] = __builtin_amdgcn_mfma_f32_16x16x32_bf16(a1, bfr[n][1], acc[m][n], 0, 0, 0);
            }
        }
        __builtin_amdgcn_s_setprio(0);
        asm volatile("s_waitcnt lgkmcnt(0)" ::: "memory");
        __builtin_amdgcn_sched_barrier(0);
        __builtin_amdgcn_s_barrier();
    }
#pragma unroll
    for (int m = 0; m < 4; ++m)
#pragma unroll
        for (int n = 0; n < 4; ++n) {
            const int col = n0 + wc * 64 + n * 16 + l15;
#pragma unroll
            for (int j = 0; j < 4; ++j) {
                const int row = m0 + wr * 64 + m * 16 + g * 4 + j;
                Cf[(size_t)row * HIDDEN + col] = acc[m][n][j] + bias[col];
            }
        }
}

extern "C" void kernel_launch(void* const* d_in, const int* in_sizes, int n_in,
                              void* d_out, int out_size, void* d_ws, size_t ws_size,
                              hipStream_t stream) {
    (void)in_sizes; (void)n_in; (void)out_size; (void)ws_size;
    const float* x  = (const float*)d_in[0];
    const float* pm = (const float*)d_in[1];
    const float* po = (const float*)d_in[2];
    const float* mw = (const float*)d_in[3];
    const float* Wq = (const float*)d_in[4];
    const float* Wk = (const float*)d_in[5];
    const float* Wv = (const float*)d_in[6];
    const float* Wo = (const float*)d_in[7];
    const float* bo = (const float*)d_in[8];
    float* out = (float*)d_out;

    char* ws = (char*)d_ws;
    const size_t SZ = (size_t)ROWS * HIDDEN;     // 4M elements
    const size_t OFF = SZ * 2;                   // 8 MB per bf16 buffer
    u16* xb    = (u16*)(ws + 0 * OFF);
    u16* Wqt   = (u16*)(ws + 1 * OFF);           // Wqt/Wkt/Wvt contiguous = Bqkv[6144][2048]
    u16* Wkt   = (u16*)(ws + 2 * OFF);
    u16* Wvt   = (u16*)(ws + 3 * OFF);
    u16* Wot   = (u16*)(ws + 4 * OFF);
    u16* qrawp = (u16*)(ws + 5 * OFF);
    u16* krawp = (u16*)(ws + 6 * OFF);
    u16* vrawp = (u16*)(ws + 7 * OFF);
    u16* vTp   = (u16*)(ws + 8 * OFF);
    u16* attnb = (u16*)(ws + 9 * OFF);
    float* cosT = (float*)(ws + 10 * OFF);
    float* sinT = (float*)(ws + 10 * OFF + 262144);

    k_prep<<<dim3(20736), 256, 0, stream>>>(x, xb, Wq, Wk, Wv, Wo,
                                            Wqt, Wkt, Wvt, Wot, cosT, sinT);
    k_qkv<<<dim3(192), 512, 0, stream>>>(xb, Wqt, qrawp, krawp, vrawp);
    k_mid<<<dim3(12288), 256, 0, stream>>>(qrawp, krawp, cosT, sinT, vrawp, vTp);
    k_attn<<<dim3(512), 256, 0, stream>>>(qrawp, krawp, vTp, pm, po, mw, attnb);
    k_out<<<dim3(256), 256, 0, stream>>>(attnb, Wot, out, bo);
}

// Round 13
// 222.686 us; speedup vs baseline: 1.1899x; 1.1899x over previous
//
#include <hip/hip_runtime.h>

typedef unsigned int u32;
typedef unsigned short u16;
typedef __bf16 bf16x8 __attribute__((ext_vector_type(8)));
typedef float f32x4 __attribute__((ext_vector_type(4)));

#define HIDDEN 2048
#define HEADS 16
#define HDIM 128
#define SEQ 1024
#define BATCH 2
#define ROWS (BATCH*SEQ)
#define SCALE 0.08838834764831845f   /* 128^-0.5 */
#define GSC 0.1f

__device__ __forceinline__ u16 f2bf(float f) {
    u32 x = __builtin_bit_cast(u32, f);
    x += 0x7fffu + ((x >> 16) & 1u);          // RNE
    return (u16)(x >> 16);
}
__device__ __forceinline__ float bf2f(u16 u) {
    return __builtin_bit_cast(float, ((u32)u) << 16);
}
__device__ __forceinline__ void gld_lds16(const void* g, void* l) {
    __builtin_amdgcn_global_load_lds((const __attribute__((address_space(1))) u32*)g,
                                     (__attribute__((address_space(3))) u32*)l, 16, 0, 0);
}

// ---------------- prep mega: x->bf16 (4096 blocks) | W^T bf16 (16384) | rope tables (256)
__global__ __launch_bounds__(256) void k_prep(
    const float* __restrict__ x, u16* __restrict__ xb,
    const float* __restrict__ W0, const float* __restrict__ W1,
    const float* __restrict__ W2, const float* __restrict__ W3,
    u16* __restrict__ T0, u16* __restrict__ T1, u16* __restrict__ T2, u16* __restrict__ T3,
    float* __restrict__ cosT, float* __restrict__ sinT) {
    __shared__ float t[32][33];
    const int bid = blockIdx.x;
    const int tid = threadIdx.x;
    if (bid < 4096) {                         // ---- cvt ----
        const int i = (bid * 256 + tid) * 4;
        float4 v = *(const float4*)(x + i);
        uint2 r;
        r.x = (u32)f2bf(v.x) | ((u32)f2bf(v.y) << 16);
        r.y = (u32)f2bf(v.z) | ((u32)f2bf(v.w) << 16);
        *(uint2*)(xb + i) = r;
    } else if (bid < 4096 + 16384) {          // ---- weight transpose+cvt ----
        const int idx = bid - 4096;
        const int bx = (idx & 63) * 32, by = ((idx >> 6) & 63) * 32, z = idx >> 12;
        const float* W = (z == 0) ? W0 : (z == 1) ? W1 : (z == 2) ? W2 : W3;
        u16* Wt = (z == 0) ? T0 : (z == 1) ? T1 : (z == 2) ? T2 : T3;
        const int tx = tid & 31, ty = tid >> 5;
#pragma unroll
        for (int yy = 0; yy < 32; yy += 8)
            t[ty + yy][tx] = W[(size_t)(by + ty + yy) * HIDDEN + bx + tx];
        __syncthreads();
#pragma unroll
        for (int yy = 0; yy < 32; yy += 8)
            Wt[(size_t)(bx + ty + yy) * HIDDEN + by + tx] = f2bf(t[tx][ty + yy]);
    } else {                                  // ---- rope tables ----
        const int i = (bid - 20480) * 256 + tid;   // 65536
        const int s = i >> 6, d = i & 63;
        const float inv = expf(-(float)d * 0.14391156831f);  // ln(10000)/64
        const float fr = (float)s * inv;
        cosT[i] = cosf(fr);
        sinT[i] = sinf(fr);
    }
}

// ---------------- QKV GEMM: 256x256 tile, counted-vmcnt double-buffer (T4+T5) ----------
__global__ __launch_bounds__(512, 2) void k_qkv(
    const u16* __restrict__ Ag, const u16* __restrict__ Bg,
    u16* __restrict__ qo, u16* __restrict__ ko, u16* __restrict__ vo) {
    __shared__ __align__(16) u16 As[2][16384];   // [buf][256 rows x 64 k]
    __shared__ __align__(16) u16 Bs[2][16384];
    const int tid = threadIdx.x;
    const int l = tid & 63, wid = tid >> 6;
    const int wr = wid >> 2, wc = wid & 3;          // 2 x 4 waves
    const int g = l >> 4, l15 = l & 15;
    const int bid = blockIdx.x;                     // 0..191
    const int idx = bid >> 3;                       // 0..23
    const int nt = (bid & 7) * 3 + idx % 3;         // 0..23
    const int mt = idx / 3;                         // 0..7
    const int m0 = mt * 256, n0 = nt * 256;
    const int swxe = (l15 & 7) << 3;                // read-side XOR (elements)
    int srow[4], scol[4];
#pragma unroll
    for (int p = 0; p < 4; ++p) {
        const int o = p * 8192 + tid * 16;
        const int r = o >> 7;
        srow[p] = r;
        scol[p] = ((o & 127) ^ ((r & 7) << 4)) >> 1;
    }
    f32x4 acc[8][4] = {};
    constexpr int NT = HIDDEN / 64;                 // 32 K-tiles

#pragma unroll
    for (int p = 0; p < 4; ++p)
        gld_lds16(Ag + (size_t)(m0 + srow[p]) * HIDDEN + scol[p], &As[0][p * 4096 + tid * 8]);
#pragma unroll
    for (int p = 0; p < 4; ++p)
        gld_lds16(Bg + (size_t)(n0 + srow[p]) * HIDDEN + scol[p], &Bs[0][p * 4096 + tid * 8]);

    for (int i = 0; i < NT; ++i) {
        const int cur = i & 1, nb = cur ^ 1;
        const bool more = (i + 1 < NT);
        if (more) {
            const int kk1 = (i + 1) * 64;
#pragma unroll
            for (int p = 0; p < 4; ++p)
                gld_lds16(Ag + (size_t)(m0 + srow[p]) * HIDDEN + kk1 + scol[p],
                          &As[nb][p * 4096 + tid * 8]);
#pragma unroll
            for (int p = 0; p < 4; ++p)
                gld_lds16(Bg + (size_t)(n0 + srow[p]) * HIDDEN + kk1 + scol[p],
                          &Bs[nb][p * 4096 + tid * 8]);
        }
        if (more) asm volatile("s_waitcnt vmcnt(8)" ::: "memory");
        else      asm volatile("s_waitcnt vmcnt(0)" ::: "memory");
        __builtin_amdgcn_sched_barrier(0);
        __builtin_amdgcn_s_barrier();
        bf16x8 bfr[4][2];
#pragma unroll
        for (int n = 0; n < 4; ++n)
#pragma unroll
            for (int ks = 0; ks < 2; ++ks)
                bfr[n][ks] = *(const bf16x8*)&Bs[cur][(wc * 64 + n * 16 + l15) * 64 +
                                                      ((ks * 32 + g * 8) ^ swxe)];
        __builtin_amdgcn_s_setprio(1);
#pragma unroll
        for (int m = 0; m < 8; ++m) {
            bf16x8 a0 = *(const bf16x8*)&As[cur][(wr * 128 + m * 16 + l15) * 64 +
                                                 ((g * 8) ^ swxe)];
            bf16x8 a1 = *(const bf16x8*)&As[cur][(wr * 128 + m * 16 + l15) * 64 +
                                                 ((32 + g * 8) ^ swxe)];
#pragma unroll
            for (int n = 0; n < 4; ++n) {
                acc[m][n] = __builtin_amdgcn_mfma_f32_16x16x32_bf16(a0, bfr[n][0], acc[m][n], 0, 0, 0);
                acc[m][n] = __builtin_amdgcn_mfma_f32_16x16x32_bf16(a1, bfr[n][1], acc[m][n], 0, 0, 0);
            }
        }
        __builtin_amdgcn_s_setprio(0);
        asm volatile("s_waitcnt lgkmcnt(0)" ::: "memory");
        __builtin_amdgcn_sched_barrier(0);
        __builtin_amdgcn_s_barrier();
    }
    u16* Cb = (nt < 8) ? qo : (nt < 16) ? ko : vo;
    const int nloc = n0 & 2047;
#pragma unroll
    for (int m = 0; m < 8; ++m)
#pragma unroll
        for (int n = 0; n < 4; ++n) {
            const int col = nloc + wc * 64 + n * 16 + l15;
#pragma unroll
            for (int j = 0; j < 4; ++j) {
                const int row = m0 + wr * 128 + m * 16 + g * 4 + j;
                Cb[(size_t)row * HIDDEN + col] = f2bf(acc[m][n][j]);
            }
        }
}

// ---------------- mid mega: RoPE in place (8192 blocks) | v -> vT (4096) ----------------
__global__ __launch_bounds__(256) void k_mid(
    u16* __restrict__ q, u16* __restrict__ k,
    const float* __restrict__ cosT, const float* __restrict__ sinT,
    const u16* __restrict__ v, u16* __restrict__ vT) {
    __shared__ u16 t[32][33];
    const int bid = blockIdx.x;
    const int tid = threadIdx.x;
    if (bid < 8192) {                          // ---- rope ----
        const int i = bid * 256 + tid;         // 2M
        const int row = i >> 10;
        const int hd = i & 1023;
        const int h = hd >> 6, d = hd & 63;
        const int s = row & (SEQ - 1);
        const float c = cosT[s * 64 + d], sn = sinT[s * 64 + d];
        const size_t o1 = (size_t)row * HIDDEN + h * HDIM + d;
        const size_t o2 = o1 + 64;
        float x1 = bf2f(q[o1]), x2 = bf2f(q[o2]);
        q[o1] = f2bf(x1 * c - x2 * sn);
        q[o2] = f2bf(x2 * c + x1 * sn);
        float y1 = bf2f(k[o1]), y2 = bf2f(k[o2]);
        k[o1] = f2bf(y1 * c - y2 * sn);
        k[o2] = f2bf(y2 * c + y1 * sn);
    } else {                                   // ---- v transpose ----
        const int idx = bid - 8192;
        const int s0 = (idx & 31) * 32, d0 = ((idx >> 5) & 3) * 32, bh = idx >> 7;
        const int b = bh >> 4, h = bh & 15;
        const int tx = tid & 31, ty = tid >> 5;
#pragma unroll
        for (int yy = 0; yy < 32; yy += 8)
            t[ty + yy][tx] = v[(size_t)(b * SEQ + s0 + ty + yy) * HIDDEN + h * HDIM + d0 + tx];
        __syncthreads();
#pragma unroll
        for (int yy = 0; yy < 32; yy += 8)
            vT[((size_t)bh * HDIM + d0 + ty + yy) * SEQ + s0 + tx] = t[tx][ty + yy];
    }
}

// ---------------- fused causal attention + in-register governance bias ------------------
// 2-wave blocks, IN-BLOCK phase pairing: phase A = q-strip (31-i), phase B = q-strip i
// (32 rows each) -> every block does exactly 17 k-tile steps (dispatch-independent
// balance, zero tail). Double-buffered K/V LDS + counted-vmcnt protocol (R9-proven):
// stage KV(kt+1)[16] + masks(kt+1)[12] -> vmcnt(28) -> barrier -> compute(kt) ->
// lgkm(0) -> barrier.  Peak outstanding 60 < 63 HW cap.
__global__ __launch_bounds__(128) void k_attn(
    const u16* __restrict__ qraw, const u16* __restrict__ kraw, const u16* __restrict__ vT,
    const float* __restrict__ pm, const float* __restrict__ po, const float* __restrict__ mw,
    u16* __restrict__ attnb) {
    __shared__ __align__(16) u16 Ks[2][8192];   // [buf][64 k x 128 d]
    __shared__ __align__(16) u16 Vs[2][8192];   // [buf][128 d x 64 k]
    __shared__ __align__(16) u16 Pl[2][16 * 72];
    const int tid = threadIdx.x;
    const int ln = tid & 63, w = tid >> 6;
    const int g = ln >> 4, q15 = ln & 15;
    const int j = blockIdx.x;            // 0..511
    const int p = j >> 3;                // 0..63 within XCD chunk
    const int y = (j & 7) * 4 + (p & 3); // head slab per XCD
    const int pairIdx = p >> 2;          // 0..15
    const int b = y >> 4, h = y & 15;
    const int k_r = tid >> 4;                                  // 0..7
    const int k_c = ((tid & 15) * 8) ^ ((k_r & 7) << 3);
    const int v_r = tid >> 3;                                  // 0..15
    const int v_c = ((tid & 7) * 8) ^ ((v_r & 7) << 3);
    const int sw = (q15 & 7) << 3;
    const u16* krow = kraw + (size_t)(b * SEQ) * HIDDEN + h * HDIM;
    const u16* vrow = vT + (size_t)y * HDIM * SEQ;
    u16* pw = &Pl[w][0];
    float4 mA[12], mB[12];

#pragma unroll 1
    for (int phase = 0; phase < 2; ++phase) {
        const int qb = (phase == 0) ? (31 - pairIdx) : pairIdx;
        const int q0 = qb * 32;
        const int qw = q0 + w * 16;
        const int qg = qw + q15;
        const int ktmax = qb >> 1;
        bf16x8 qf[4];
        {
            const size_t qoff = (size_t)(b * SEQ + qg) * HIDDEN + h * HDIM;
#pragma unroll
            for (int ds = 0; ds < 4; ++ds)
                qf[ds] = *(const bf16x8*)(qraw + qoff + ds * 32 + g * 8);
        }
        f32x4 acc_o[8] = {};
        float m_run = -1e30f, l_run = 0.f;
        const size_t mbase = ((size_t)y * SEQ + qg) * SEQ + g * 4;
        const float* pmr = pm + mbase;
        const float* por = po + mbase;
        const float* mwr = mw + mbase;

        auto stage_kv = [&](int kt, int bufi) {
            const int k0 = kt * 64;
#pragma unroll
            for (int c = 0; c < 8; ++c)
                gld_lds16(krow + (size_t)(k0 + c * 8 + k_r) * HIDDEN + k_c,
                          &Ks[bufi][c * 1024 + tid * 8]);
#pragma unroll
            for (int c = 0; c < 8; ++c)
                gld_lds16(vrow + (size_t)(c * 16 + v_r) * SEQ + k0 + v_c,
                          &Vs[bufi][c * 1024 + tid * 8]);
        };
        auto issue_masks = [&](float4 (&mm)[12], int kt) {
            const int c = kt * 64;
#pragma unroll
            for (int m = 0; m < 4; ++m) {
                mm[m * 3 + 0] = *(const float4*)(pmr + c + m * 16);
                mm[m * 3 + 1] = *(const float4*)(por + c + m * 16);
                mm[m * 3 + 2] = *(const float4*)(mwr + c + m * 16);
            }
        };

        auto step = [&](int kt, float4 (&cur)[12], float4 (&nxt)[12]) {
            const int bufi = kt & 1;
            const bool more = (kt < ktmax);
            // (1) stage next tile's K/V (16 gld_lds) + masks (12 loads): 28/thread
            if (more) {
                stage_kv(kt + 1, bufi ^ 1);
                issue_masks(nxt, kt + 1);
            }
            // (2) counted wait BEFORE barrier: tile kt's loads retired for this wave;
            //     barrier upgrades to all waves.  Never drains to 0 mid-loop.
            if (more) asm volatile("s_waitcnt vmcnt(28)" ::: "memory");
            else      asm volatile("s_waitcnt vmcnt(0)" ::: "memory");
            __builtin_amdgcn_sched_barrier(0);
            __builtin_amdgcn_s_barrier();
            // (3) QK^T from Ks[bufi]
            const int k0 = kt * 64;
            f32x4 accs[4] = {};
#pragma unroll
            for (int ds = 0; ds < 4; ++ds)
#pragma unroll
                for (int m = 0; m < 4; ++m) {
                    bf16x8 kf = *(const bf16x8*)&Ks[bufi][(m * 16 + q15) * 128 +
                                                          ((ds * 32 + g * 8) ^ sw)];
                    accs[m] = __builtin_amdgcn_mfma_f32_16x16x32_bf16(kf, qf[ds], accs[m], 0, 0, 0);
                }
            // (4) bias + causal + online softmax
            float pmax = -1e30f;
#pragma unroll
            for (int m = 0; m < 4; ++m) {
                const float4 av = cur[m * 3 + 0];
                const float4 bv4 = cur[m * 3 + 1];
                const float4 cv = cur[m * 3 + 2];
#pragma unroll
                for (int r = 0; r < 4; ++r) {
                    const int kglob = k0 + m * 16 + g * 4 + r;
                    const float bias = (&av.x)[r] * (GSC * 0.5f) + (&bv4.x)[r] * GSC +
                                       __logf(fmaf((&cv.x)[r], GSC, 1.0f + 1e-8f));
                    float s = (kglob <= qg) ? fmaf(accs[m][r], SCALE, bias) : -1e30f;
                    accs[m][r] = s;
                    pmax = fmaxf(pmax, s);
                }
            }
            pmax = fmaxf(pmax, __shfl_xor(pmax, 16));
            pmax = fmaxf(pmax, __shfl_xor(pmax, 32));
            const float mnew = fmaxf(m_run, pmax);
            const float alpha = __expf(m_run - mnew);
            float lsum = 0.f;
#pragma unroll
            for (int m = 0; m < 4; ++m)
#pragma unroll
                for (int r = 0; r < 4; ++r) {
                    float e = __expf(accs[m][r] - mnew);
                    accs[m][r] = e;
                    lsum += e;
                }
            lsum += __shfl_xor(lsum, 16);
            lsum += __shfl_xor(lsum, 32);
            l_run = l_run * alpha + lsum;
            m_run = mnew;
#pragma unroll
            for (int m = 0; m < 4; ++m) {
                uint2 pk;
                pk.x = (u32)f2bf(accs[m][0]) | ((u32)f2bf(accs[m][1]) << 16);
                pk.y = (u32)f2bf(accs[m][2]) | ((u32)f2bf(accs[m][3]) << 16);
                *(uint2*)&pw[q15 * 72 + m * 16 + g * 4] = pk;
            }
            float al[4];
#pragma unroll
            for (int jj = 0; jj < 4; ++jj) al[jj] = __shfl(alpha, g * 4 + jj);
#pragma unroll
            for (int n = 0; n < 8; ++n)
#pragma unroll
                for (int jj = 0; jj < 4; ++jj) acc_o[n][jj] *= al[jj];
            // (5) PV from Vs[bufi]
#pragma unroll
            for (int c = 0; c < 2; ++c) {
                const bf16x8 af = *(const bf16x8*)&pw[q15 * 72 + c * 32 + g * 8];
#pragma unroll
                for (int n = 0; n < 8; ++n) {
                    const bf16x8 vf = *(const bf16x8*)&Vs[bufi][(n * 16 + q15) * 64 +
                                                               ((c * 32 + g * 8) ^ sw)];
                    acc_o[n] = __builtin_amdgcn_mfma_f32_16x16x32_bf16(af, vf, acc_o[n], 0, 0, 0);
                }
            }
            // (6) LDS reads done -> safe for next overwrite after barrier
            asm volatile("s_waitcnt lgkmcnt(0)" ::: "memory");
            __builtin_amdgcn_sched_barrier(0);
            __builtin_amdgcn_s_barrier();
        };

        stage_kv(0, 0);
        issue_masks(mA, 0);
        int kt = 0;
        for (;;) {
            step(kt, mA, mB);
            if (kt == ktmax) break;
            ++kt;
            step(kt, mB, mA);
            if (kt == ktmax) break;
            ++kt;
        }

        const float linv = 1.0f / l_run;
        float li[4];
#pragma unroll
        for (int jj = 0; jj < 4; ++jj) li[jj] = __shfl(linv, g * 4 + jj);
#pragma unroll
        for (int n = 0; n < 8; ++n)
#pragma unroll
            for (int jj = 0; jj < 4; ++jj) {
                const int row = b * SEQ + qw + g * 4 + jj;
                const int col = h * HDIM + n * 16 + q15;
                attnb[(size_t)row * HIDDEN + col] = f2bf(acc_o[n][jj] * li[jj]);
            }
    }
}

// ---------------- output GEMM: 128x128 tile, counted-vmcnt double-buffer ----------------
__global__ __launch_bounds__(256) void k_out(
    const u16* __restrict__ A, const u16* __restrict__ Bt,
    float* __restrict__ Cf, const float* __restrict__ bias) {
    __shared__ __align__(16) u16 As[2][8192];    // [buf][128 rows x 64 k]
    __shared__ __align__(16) u16 Bs[2][8192];
    const int tid = threadIdx.x;
    const int l = tid & 63, wid = tid >> 6;
    const int wr = wid >> 1, wc = wid & 1;        // 2 x 2 waves
    const int g = l >> 4, l15 = l & 15;
    const int bid = blockIdx.x;                   // 0..255, XCD-bijective (256%8==0)
    const int rr = (bid & 7) * 32 + (bid >> 3);
    const int mt = rr >> 4, nt = rr & 15;
    const int m0 = mt * 128, n0 = nt * 128;
    const int swxe = (l15 & 7) << 3;
    int srow[4], scol[4];
#pragma unroll
    for (int p = 0; p < 4; ++p) {
        const int o = p * 4096 + tid * 16;
        const int r = o >> 7;                     // 0..127
        srow[p] = r;
        scol[p] = ((o & 127) ^ ((r & 7) << 4)) >> 1;
    }
    f32x4 acc[4][4] = {};
    constexpr int NT = HIDDEN / 64;               // 32 K-tiles

#pragma unroll
    for (int p = 0; p < 4; ++p) {
        gld_lds16(A + (size_t)(m0 + srow[p]) * HIDDEN + scol[p], &As[0][p * 2048 + tid * 8]);
        gld_lds16(Bt + (size_t)(n0 + srow[p]) * HIDDEN + scol[p], &Bs[0][p * 2048 + tid * 8]);
    }

    for (int i = 0; i < NT; ++i) {
        const int cur = i & 1, nb = cur ^ 1;
        const bool more = (i + 1 < NT);
        if (more) {
            const int kk1 = (i + 1) * 64;
#pragma unroll
            for (int p = 0; p < 4; ++p) {
                gld_lds16(A + (size_t)(m0 + srow[p]) * HIDDEN + kk1 + scol[p],
                          &As[nb][p * 2048 + tid * 8]);
                gld_lds16(Bt + (size_t)(n0 + srow[p]) * HIDDEN + kk1 + scol[p],
                          &Bs[nb][p * 2048 + tid * 8]);
            }
        }
        if (more) asm volatile("s_waitcnt vmcnt(8)" ::: "memory");
        else      asm volatile("s_waitcnt vmcnt(0)" ::: "memory");
        __builtin_amdgcn_sched_barrier(0);
        __builtin_amdgcn_s_barrier();
        bf16x8 bfr[4][2];
#pragma unroll
        for (int n = 0; n < 4; ++n)
#pragma unroll
            for (int ks = 0; ks < 2; ++ks)
                bfr[n][ks] = *(const bf16x8*)&Bs[cur][(wc * 64 + n * 16 + l15) * 64 +
                                                      ((ks * 32 + g * 8) ^ swxe)];
        __builtin_amdgcn_s_setprio(1);
#pragma unroll
        for (int m = 0; m < 4; ++m) {
            bf16x8 a0 = *(const bf16x8*)&As[cur][(wr * 64 + m * 16 + l15) * 64 +
                                                 ((g * 8) ^ swxe)];
            bf16x8 a1 = *(const bf16x8*)&As[cur][(wr * 64 + m * 16 + l15) * 64 +
                                                 ((32 + g * 8) ^ swxe)];
#pragma unroll
            for (int n = 0; n < 4; ++n) {
                acc[m][n] = __builtin_amdgcn_mfma_f32_16x16x32_bf16(a0, bfr[n][0], acc[m][n], 0, 0, 0);
                acc[m][n] = __builtin_amdgcn_mfma_f32_16x16x32_bf16(a1, bfr[n][1], acc[m][n], 0, 0, 0);
            }
        }
        __builtin_amdgcn_s_setprio(0);
        asm volatile("s_waitcnt lgkmcnt(0)" ::: "memory");
        __builtin_amdgcn_sched_barrier(0);
        __builtin_amdgcn_s_barrier();
    }
#pragma unroll
    for (int m = 0; m < 4; ++m)
#pragma unroll
        for (int n = 0; n < 4; ++n) {
            const int col = n0 + wc * 64 + n * 16 + l15;
#pragma unroll
            for (int j = 0; j < 4; ++j) {
                const int row = m0 + wr * 64 + m * 16 + g * 4 + j;
                Cf[(size_t)row * HIDDEN + col] = acc[m][n][j] + bias[col];
            }
        }
}

extern "C" void kernel_launch(void* const* d_in, const int* in_sizes, int n_in,
                              void* d_out, int out_size, void* d_ws, size_t ws_size,
                              hipStream_t stream) {
    (void)in_sizes; (void)n_in; (void)out_size; (void)ws_size;
    const float* x  = (const float*)d_in[0];
    const float* pm = (const float*)d_in[1];
    const float* po = (const float*)d_in[2];
    const float* mw = (const float*)d_in[3];
    const float* Wq = (const float*)d_in[4];
    const float* Wk = (const float*)d_in[5];
    const float* Wv = (const float*)d_in[6];
    const float* Wo = (const float*)d_in[7];
    const float* bo = (const float*)d_in[8];
    float* out = (float*)d_out;

    char* ws = (char*)d_ws;
    const size_t SZ = (size_t)ROWS * HIDDEN;     // 4M elements
    const size_t OFF = SZ * 2;                   // 8 MB per bf16 buffer
    u16* xb    = (u16*)(ws + 0 * OFF);
    u16* Wqt   = (u16*)(ws + 1 * OFF);           // Wqt/Wkt/Wvt contiguous = Bqkv[6144][2048]
    u16* Wkt   = (u16*)(ws + 2 * OFF);
    u16* Wvt   = (u16*)(ws + 3 * OFF);
    u16* Wot   = (u16*)(ws + 4 * OFF);
    u16* qrawp = (u16*)(ws + 5 * OFF);
    u16* krawp = (u16*)(ws + 6 * OFF);
    u16* vrawp = (u16*)(ws + 7 * OFF);
    u16* vTp   = (u16*)(ws + 8 * OFF);
    u16* attnb = (u16*)(ws + 9 * OFF);
    float* cosT = (float*)(ws + 10 * OFF);
    float* sinT = (float*)(ws + 10 * OFF + 262144);

    k_prep<<<dim3(20736), 256, 0, stream>>>(x, xb, Wq, Wk, Wv, Wo,
                                            Wqt, Wkt, Wvt, Wot, cosT, sinT);
    k_qkv<<<dim3(192), 512, 0, stream>>>(xb, Wqt, qrawp, krawp, vrawp);
    k_mid<<<dim3(12288), 256, 0, stream>>>(qrawp, krawp, cosT, sinT, vrawp, vTp);
    k_attn<<<dim3(512), 128, 0, stream>>>(qrawp, krawp, vTp, pm, po, mw, attnb);
    k_out<<<dim3(256), 256, 0, stream>>>(attnb, Wot, out, bo);
}